// Round 1
// baseline (575.790 us; speedup 1.0000x reference)
//
#include <hip/hip_runtime.h>

#define NN 50000
#define NE 600000
#define F 128

// ---------------- graph prep ----------------

__global__ void count_deg(const int* __restrict__ dst, int* __restrict__ deg, int E) {
    int e = blockIdx.x * blockDim.x + threadIdx.x;
    if (e < E) atomicAdd(&deg[dst[e]], 1);
}

__global__ __launch_bounds__(1024) void scan_offsets(const int* __restrict__ deg,
                                                     int* __restrict__ off,
                                                     int* __restrict__ cur,
                                                     float* __restrict__ recip, int N) {
    __shared__ int s[1024];
    int tid = threadIdx.x;
    int running = 0;
    for (int base = 0; base < N; base += 1024) {
        int idx = base + tid;
        int v = (idx < N) ? deg[idx] : 0;
        s[tid] = v;
        __syncthreads();
        #pragma unroll
        for (int o = 1; o < 1024; o <<= 1) {
            int t = (tid >= o) ? s[tid - o] : 0;
            __syncthreads();
            s[tid] += t;
            __syncthreads();
        }
        int incl = s[tid];
        if (idx < N) {
            int start = running + incl - v;
            off[idx] = start;
            cur[idx] = start;
            recip[idx] = 1.0f / (float)max(v, 1);
        }
        running += s[1023];
        __syncthreads();
    }
}

__global__ void fill_csr(const int* __restrict__ src, const int* __restrict__ dst,
                         int* __restrict__ cur, int* __restrict__ csr, int E) {
    int e = blockIdx.x * blockDim.x + threadIdx.x;
    if (e < E) {
        int pos = atomicAdd(&cur[dst[e]], 1);
        csr[pos] = src[e];
    }
}

// ---------------- mean aggregation (one wave per node) ----------------

__global__ __launch_bounds__(256) void agg_mean(const float* __restrict__ x,
                                                const int* __restrict__ off,
                                                const int* __restrict__ deg,
                                                const float* __restrict__ recip,
                                                const int* __restrict__ csr,
                                                float* __restrict__ mean, int N) {
    int node = blockIdx.x * 4 + (threadIdx.x >> 6);
    if (node >= N) return;
    int lane = threadIdx.x & 63;
    int start = off[node];
    int d = deg[node];
    const float2* xp = (const float2*)x;
    float ax = 0.f, ay = 0.f;
    int i = 0;
    for (; i + 1 < d; i += 2) {
        int s0 = csr[start + i];
        int s1 = csr[start + i + 1];
        float2 v0 = xp[(size_t)s0 * 64 + lane];
        float2 v1 = xp[(size_t)s1 * 64 + lane];
        ax += v0.x + v1.x;
        ay += v0.y + v1.y;
    }
    if (i < d) {
        int s0 = csr[start + i];
        float2 v0 = xp[(size_t)s0 * 64 + lane];
        ax += v0.x;
        ay += v0.y;
    }
    float r = recip[node];
    float2 o;
    o.x = ax * r;
    o.y = ay * r;
    ((float2*)mean)[(size_t)node * 64 + lane] = o;
}

// ---------------- fused SAGE GEMM: out = act(x@Ws + mean@Wn + b) ----------------
// 64 rows x 128 cols per block, 256 threads, each thread 8 rows x 4 cols.
// In-place safe (x == out): full K staged to LDS before any writes.

template <int RELU>
__global__ __launch_bounds__(256) void sage_gemm(const float* __restrict__ x,
                                                 const float* __restrict__ mean,
                                                 const float* __restrict__ Ws,
                                                 const float* __restrict__ Wn,
                                                 const float* __restrict__ bias,
                                                 float* __restrict__ out, int N) {
    __shared__ float sx[64][128];
    __shared__ float sm[64][128];
    int tid = threadIdx.x;
    int r0 = blockIdx.x * 64;

    // stage A panels: 2048 float4 slots each, 8 per thread
    #pragma unroll
    for (int j = 0; j < 8; ++j) {
        int idx = tid + j * 256;
        int row = idx >> 5;
        int c4 = idx & 31;
        float4 vx = make_float4(0.f, 0.f, 0.f, 0.f);
        float4 vm = make_float4(0.f, 0.f, 0.f, 0.f);
        if (r0 + row < N) {
            vx = ((const float4*)x)[(size_t)(r0 + row) * 32 + c4];
            vm = ((const float4*)mean)[(size_t)(r0 + row) * 32 + c4];
        }
        *(float4*)&sx[row][c4 * 4] = vx;
        *(float4*)&sm[row][c4 * 4] = vm;
    }
    __syncthreads();

    int cg = (tid & 31) * 4;
    int rg = (tid >> 5) * 8;
    float acc[8][4];
    #pragma unroll
    for (int i = 0; i < 8; ++i)
        #pragma unroll
        for (int j = 0; j < 4; ++j) acc[i][j] = 0.f;

    for (int k = 0; k < 128; ++k) {
        float4 ws = *(const float4*)&Ws[k * 128 + cg];
        float4 wn = *(const float4*)&Wn[k * 128 + cg];
        #pragma unroll
        for (int i = 0; i < 8; ++i) {
            float a = sx[rg + i][k];
            float m = sm[rg + i][k];
            acc[i][0] = fmaf(a, ws.x, fmaf(m, wn.x, acc[i][0]));
            acc[i][1] = fmaf(a, ws.y, fmaf(m, wn.y, acc[i][1]));
            acc[i][2] = fmaf(a, ws.z, fmaf(m, wn.z, acc[i][2]));
            acc[i][3] = fmaf(a, ws.w, fmaf(m, wn.w, acc[i][3]));
        }
    }

    float4 bb = *(const float4*)&bias[cg];
    #pragma unroll
    for (int i = 0; i < 8; ++i) {
        int row = r0 + rg + i;
        if (row < N) {
            float4 o;
            o.x = acc[i][0] + bb.x;
            o.y = acc[i][1] + bb.y;
            o.z = acc[i][2] + bb.z;
            o.w = acc[i][3] + bb.w;
            if (RELU) {
                o.x = fmaxf(o.x, 0.f);
                o.y = fmaxf(o.y, 0.f);
                o.z = fmaxf(o.z, 0.f);
                o.w = fmaxf(o.w, 0.f);
            }
            ((float4*)out)[(size_t)row * 32 + (cg >> 2)] = o;
        }
    }
}

// ---------------- launch ----------------

extern "C" void kernel_launch(void* const* d_in, const int* in_sizes, int n_in,
                              void* d_out, int out_size, void* d_ws, size_t ws_size,
                              hipStream_t stream) {
    const float* feat = (const float*)d_in[0];
    const int* src = (const int*)d_in[1];
    const int* dst = (const int*)d_in[2];
    const float* W1s = (const float*)d_in[3];
    const float* W1n = (const float*)d_in[4];
    const float* b1 = (const float*)d_in[5];
    const float* W2s = (const float*)d_in[6];
    const float* W2n = (const float*)d_in[7];
    const float* b2 = (const float*)d_in[8];
    const float* W3s = (const float*)d_in[9];
    const float* W3n = (const float*)d_in[10];
    const float* b3 = (const float*)d_in[11];
    float* out = (float*)d_out;

    const int N = NN, E = NE;

    char* p = (char*)d_ws;
    auto alloc = [&](size_t bytes) {
        char* q = p;
        p += (bytes + 255) & ~(size_t)255;
        return q;
    };
    int* deg = (int*)alloc((size_t)N * 4);
    int* off = (int*)alloc((size_t)N * 4);
    int* cur = (int*)alloc((size_t)N * 4);
    float* recip = (float*)alloc((size_t)N * 4);
    int* csr = (int*)alloc((size_t)E * 4);
    float* mean = (float*)alloc((size_t)N * F * 4);
    float* h1 = (float*)alloc((size_t)N * F * 4);

    hipMemsetAsync(deg, 0, (size_t)N * 4, stream);
    count_deg<<<(E + 255) / 256, 256, 0, stream>>>(dst, deg, E);
    scan_offsets<<<1, 1024, 0, stream>>>(deg, off, cur, recip, N);
    fill_csr<<<(E + 255) / 256, 256, 0, stream>>>(src, dst, cur, csr, E);

    int aggGrid = (N + 3) / 4;
    int gemmGrid = (N + 63) / 64;

    // layer 1: x = feat -> h1 (relu)
    agg_mean<<<aggGrid, 256, 0, stream>>>(feat, off, deg, recip, csr, mean, N);
    sage_gemm<1><<<gemmGrid, 256, 0, stream>>>(feat, mean, W1s, W1n, b1, h1, N);
    // layer 2: x = h1 -> out (relu)
    agg_mean<<<aggGrid, 256, 0, stream>>>(h1, off, deg, recip, csr, mean, N);
    sage_gemm<1><<<gemmGrid, 256, 0, stream>>>(h1, mean, W2s, W2n, b2, out, N);
    // layer 3: x = out -> out (no relu, in-place safe)
    agg_mean<<<aggGrid, 256, 0, stream>>>(out, off, deg, recip, csr, mean, N);
    sage_gemm<0><<<gemmGrid, 256, 0, stream>>>(out, mean, W3s, W3n, b3, out, N);
}

// Round 2
// 444.363 us; speedup vs baseline: 1.2958x; 1.2958x over previous
//
#include <hip/hip_runtime.h>

#define NN 50000
#define NE 600000
#define F 128

// ---------------- graph prep ----------------

__global__ void count_deg(const int* __restrict__ dst, int* __restrict__ deg, int E) {
    int e = blockIdx.x * blockDim.x + threadIdx.x;
    if (e < E) atomicAdd(&deg[dst[e]], 1);
}

__global__ __launch_bounds__(1024) void scan_offsets(const int* __restrict__ deg,
                                                     int* __restrict__ off,
                                                     int* __restrict__ cur,
                                                     float* __restrict__ recip, int N) {
    __shared__ int wsum[17];
    int tid = threadIdx.x;
    int wid = tid >> 6;
    int lane = tid & 63;
    int running = 0;
    for (int base = 0; base < N; base += 1024) {
        int idx = base + tid;
        int v = (idx < N) ? deg[idx] : 0;
        // wave-level inclusive scan (no barriers)
        int x = v;
        #pragma unroll
        for (int o = 1; o < 64; o <<= 1) {
            int t = __shfl_up(x, o);
            if (lane >= o) x += t;
        }
        if (lane == 63) wsum[wid] = x;
        __syncthreads();
        if (tid == 0) {
            int a = 0;
            #pragma unroll
            for (int w = 0; w < 16; ++w) { int t = wsum[w]; wsum[w] = a; a += t; }
            wsum[16] = a;
        }
        __syncthreads();
        int incl = x + wsum[wid];
        if (idx < N) {
            int start = running + incl - v;
            off[idx] = start;
            cur[idx] = start;
            recip[idx] = 1.0f / (float)max(v, 1);
        }
        running += wsum[16];
        __syncthreads();
    }
}

__global__ void fill_csr(const int* __restrict__ src, const int* __restrict__ dst,
                         int* __restrict__ cur, int* __restrict__ csr, int E) {
    int e = blockIdx.x * blockDim.x + threadIdx.x;
    if (e < E) {
        int pos = atomicAdd(&cur[dst[e]], 1);
        csr[pos] = src[e];
    }
}

// ---------------- mean aggregation (one wave per node, 4-edge unroll) ----------------

__global__ __launch_bounds__(256) void agg_mean(const float* __restrict__ x,
                                                const int* __restrict__ off,
                                                const int* __restrict__ deg,
                                                const float* __restrict__ recip,
                                                const int* __restrict__ csr,
                                                float* __restrict__ mean, int N) {
    int node = blockIdx.x * 4 + (threadIdx.x >> 6);
    if (node >= N) return;
    int lane = threadIdx.x & 63;
    int start = off[node];
    int d = deg[node];
    const float2* xp = (const float2*)x;
    float ax = 0.f, ay = 0.f;
    int i = 0;
    for (; i + 4 <= d; i += 4) {
        int s0 = csr[start + i];
        int s1 = csr[start + i + 1];
        int s2 = csr[start + i + 2];
        int s3 = csr[start + i + 3];
        float2 v0 = xp[(size_t)s0 * 64 + lane];
        float2 v1 = xp[(size_t)s1 * 64 + lane];
        float2 v2 = xp[(size_t)s2 * 64 + lane];
        float2 v3 = xp[(size_t)s3 * 64 + lane];
        ax += (v0.x + v1.x) + (v2.x + v3.x);
        ay += (v0.y + v1.y) + (v2.y + v3.y);
    }
    for (; i < d; ++i) {
        int s0 = csr[start + i];
        float2 v0 = xp[(size_t)s0 * 64 + lane];
        ax += v0.x;
        ay += v0.y;
    }
    float r = recip[node];
    float2 o;
    o.x = ax * r;
    o.y = ay * r;
    ((float2*)mean)[(size_t)node * 64 + lane] = o;
}

// ---------------- fused SAGE GEMM: out = act(x@Ws + mean@Wn + b) ----------------
// 32 rows x 128 cols per block (32 KB LDS -> 5 blocks/CU), 256 threads,
// each thread 4 rows x 4 cols. In-place safe (x == out): block stages its
// full 32 rows to LDS before writing only those rows.

template <int RELU>
__global__ __launch_bounds__(256) void sage_gemm(const float* __restrict__ x,
                                                 const float* __restrict__ mean,
                                                 const float* __restrict__ Ws,
                                                 const float* __restrict__ Wn,
                                                 const float* __restrict__ bias,
                                                 float* __restrict__ out, int N) {
    __shared__ float sx[32][128];
    __shared__ float sm[32][128];
    int tid = threadIdx.x;
    int r0 = blockIdx.x * 32;

    // stage A panels: 1024 float4 slots each, 4 per thread
    #pragma unroll
    for (int j = 0; j < 4; ++j) {
        int idx = tid + j * 256;
        int row = idx >> 5;
        int c4 = idx & 31;
        float4 vx = make_float4(0.f, 0.f, 0.f, 0.f);
        float4 vm = make_float4(0.f, 0.f, 0.f, 0.f);
        if (r0 + row < N) {
            vx = ((const float4*)x)[(size_t)(r0 + row) * 32 + c4];
            vm = ((const float4*)mean)[(size_t)(r0 + row) * 32 + c4];
        }
        *(float4*)&sx[row][c4 * 4] = vx;
        *(float4*)&sm[row][c4 * 4] = vm;
    }
    __syncthreads();

    int cg = (tid & 31) * 4;
    int rg = (tid >> 5) * 4;
    float acc[4][4];
    #pragma unroll
    for (int i = 0; i < 4; ++i)
        #pragma unroll
        for (int j = 0; j < 4; ++j) acc[i][j] = 0.f;

    // software-pipelined W row loads
    float4 ws = *(const float4*)&Ws[0 * 128 + cg];
    float4 wn = *(const float4*)&Wn[0 * 128 + cg];
    for (int k = 0; k < 128; ++k) {
        int kn = (k + 1 < 128) ? (k + 1) : 127;
        float4 wsn = *(const float4*)&Ws[kn * 128 + cg];
        float4 wnn = *(const float4*)&Wn[kn * 128 + cg];
        #pragma unroll
        for (int i = 0; i < 4; ++i) {
            float a = sx[rg + i][k];
            float m = sm[rg + i][k];
            acc[i][0] = fmaf(a, ws.x, fmaf(m, wn.x, acc[i][0]));
            acc[i][1] = fmaf(a, ws.y, fmaf(m, wn.y, acc[i][1]));
            acc[i][2] = fmaf(a, ws.z, fmaf(m, wn.z, acc[i][2]));
            acc[i][3] = fmaf(a, ws.w, fmaf(m, wn.w, acc[i][3]));
        }
        ws = wsn;
        wn = wnn;
    }

    float4 bb = *(const float4*)&bias[cg];
    #pragma unroll
    for (int i = 0; i < 4; ++i) {
        int row = r0 + rg + i;
        if (row < N) {
            float4 o;
            o.x = acc[i][0] + bb.x;
            o.y = acc[i][1] + bb.y;
            o.z = acc[i][2] + bb.z;
            o.w = acc[i][3] + bb.w;
            if (RELU) {
                o.x = fmaxf(o.x, 0.f);
                o.y = fmaxf(o.y, 0.f);
                o.z = fmaxf(o.z, 0.f);
                o.w = fmaxf(o.w, 0.f);
            }
            ((float4*)out)[(size_t)row * 32 + (cg >> 2)] = o;
        }
    }
}

// ---------------- launch ----------------

extern "C" void kernel_launch(void* const* d_in, const int* in_sizes, int n_in,
                              void* d_out, int out_size, void* d_ws, size_t ws_size,
                              hipStream_t stream) {
    const float* feat = (const float*)d_in[0];
    const int* src = (const int*)d_in[1];
    const int* dst = (const int*)d_in[2];
    const float* W1s = (const float*)d_in[3];
    const float* W1n = (const float*)d_in[4];
    const float* b1 = (const float*)d_in[5];
    const float* W2s = (const float*)d_in[6];
    const float* W2n = (const float*)d_in[7];
    const float* b2 = (const float*)d_in[8];
    const float* W3s = (const float*)d_in[9];
    const float* W3n = (const float*)d_in[10];
    const float* b3 = (const float*)d_in[11];
    float* out = (float*)d_out;

    const int N = NN, E = NE;

    char* p = (char*)d_ws;
    auto alloc = [&](size_t bytes) {
        char* q = p;
        p += (bytes + 255) & ~(size_t)255;
        return q;
    };
    int* deg = (int*)alloc((size_t)N * 4);
    int* off = (int*)alloc((size_t)N * 4);
    int* cur = (int*)alloc((size_t)N * 4);
    float* recip = (float*)alloc((size_t)N * 4);
    int* csr = (int*)alloc((size_t)E * 4);
    float* mean = (float*)alloc((size_t)N * F * 4);
    float* h1 = (float*)alloc((size_t)N * F * 4);

    hipMemsetAsync(deg, 0, (size_t)N * 4, stream);
    count_deg<<<(E + 255) / 256, 256, 0, stream>>>(dst, deg, E);
    scan_offsets<<<1, 1024, 0, stream>>>(deg, off, cur, recip, N);
    fill_csr<<<(E + 255) / 256, 256, 0, stream>>>(src, dst, cur, csr, E);

    int aggGrid = (N + 3) / 4;
    int gemmGrid = (N + 31) / 32;

    // layer 1: x = feat -> h1 (relu)
    agg_mean<<<aggGrid, 256, 0, stream>>>(feat, off, deg, recip, csr, mean, N);
    sage_gemm<1><<<gemmGrid, 256, 0, stream>>>(feat, mean, W1s, W1n, b1, h1, N);
    // layer 2: x = h1 -> out (relu)
    agg_mean<<<aggGrid, 256, 0, stream>>>(h1, off, deg, recip, csr, mean, N);
    sage_gemm<1><<<gemmGrid, 256, 0, stream>>>(h1, mean, W2s, W2n, b2, out, N);
    // layer 3: x = out -> out (no relu, in-place safe)
    agg_mean<<<aggGrid, 256, 0, stream>>>(out, off, deg, recip, csr, mean, N);
    sage_gemm<0><<<gemmGrid, 256, 0, stream>>>(out, mean, W3s, W3n, b3, out, N);
}

// Round 3
// 434.107 us; speedup vs baseline: 1.3264x; 1.0236x over previous
//
#include <hip/hip_runtime.h>

#define NN 50000
#define NE 600000
#define F 128

// ---------------- graph prep ----------------

__global__ void count_deg(const int* __restrict__ dst, int* __restrict__ deg, int E) {
    int e = blockIdx.x * blockDim.x + threadIdx.x;
    if (e < E) atomicAdd(&deg[dst[e]], 1);
}

__global__ __launch_bounds__(1024) void scan_offsets(const int* __restrict__ deg,
                                                     int* __restrict__ off,
                                                     int* __restrict__ cur,
                                                     float* __restrict__ recip, int N) {
    __shared__ int wsum[17];
    int tid = threadIdx.x;
    int wid = tid >> 6;
    int lane = tid & 63;
    int running = 0;
    for (int base = 0; base < N; base += 1024) {
        int idx = base + tid;
        int v = (idx < N) ? deg[idx] : 0;
        int x = v;
        #pragma unroll
        for (int o = 1; o < 64; o <<= 1) {
            int t = __shfl_up(x, o);
            if (lane >= o) x += t;
        }
        if (lane == 63) wsum[wid] = x;
        __syncthreads();
        if (tid == 0) {
            int a = 0;
            #pragma unroll
            for (int w = 0; w < 16; ++w) { int t = wsum[w]; wsum[w] = a; a += t; }
            wsum[16] = a;
        }
        __syncthreads();
        int incl = x + wsum[wid];
        if (idx < N) {
            int start = running + incl - v;
            off[idx] = start;
            cur[idx] = start;
            recip[idx] = 1.0f / (float)max(v, 1);
        }
        running += wsum[16];
        __syncthreads();
    }
}

__global__ void fill_csr(const int* __restrict__ src, const int* __restrict__ dst,
                         int* __restrict__ cur, int* __restrict__ csr, int E) {
    int e = blockIdx.x * blockDim.x + threadIdx.x;
    if (e < E) {
        int pos = atomicAdd(&cur[dst[e]], 1);
        csr[pos] = src[e];
    }
}

// ---------------- mean aggregation (one wave per node, 8-edge unroll) ----------------

__global__ __launch_bounds__(256) void agg_mean(const float* __restrict__ x,
                                                const int* __restrict__ off,
                                                const int* __restrict__ deg,
                                                const float* __restrict__ recip,
                                                const int* __restrict__ csr,
                                                float* __restrict__ mean, int N) {
    int node = blockIdx.x * 4 + (threadIdx.x >> 6);
    if (node >= N) return;
    int lane = threadIdx.x & 63;
    int start = off[node];
    int d = deg[node];
    const float2* xp = (const float2*)x;
    float ax = 0.f, ay = 0.f;
    int i = 0;
    for (; i + 8 <= d; i += 8) {
        int s[8];
        #pragma unroll
        for (int u = 0; u < 8; ++u) s[u] = csr[start + i + u];
        float2 v[8];
        #pragma unroll
        for (int u = 0; u < 8; ++u) v[u] = xp[(size_t)s[u] * 64 + lane];
        #pragma unroll
        for (int u = 0; u < 8; ++u) { ax += v[u].x; ay += v[u].y; }
    }
    if (i + 4 <= d) {
        int s[4];
        #pragma unroll
        for (int u = 0; u < 4; ++u) s[u] = csr[start + i + u];
        float2 v[4];
        #pragma unroll
        for (int u = 0; u < 4; ++u) v[u] = xp[(size_t)s[u] * 64 + lane];
        #pragma unroll
        for (int u = 0; u < 4; ++u) { ax += v[u].x; ay += v[u].y; }
        i += 4;
    }
    for (; i < d; ++i) {
        int s0 = csr[start + i];
        float2 v0 = xp[(size_t)s0 * 64 + lane];
        ax += v0.x;
        ay += v0.y;
    }
    float r = recip[node];
    float2 o;
    o.x = ax * r;
    o.y = ay * r;
    ((float2*)mean)[(size_t)node * 64 + lane] = o;
}

// ---------------- fused SAGE GEMM: out = act(x@Ws + mean@Wn + b) ----------------
// 32 rows x 128 cols per block (32 KB LDS), 256 threads, each thread 4 rows x
// 4 cols. k-loop unrolled x4 with 4-deep W-row prefetch (8 float4 loads in
// flight) to hide L2 latency. In-place safe (x == out): block stages its full
// 32 rows to LDS before writing only those rows.

template <int RELU>
__global__ __launch_bounds__(256) void sage_gemm(const float* __restrict__ x,
                                                 const float* __restrict__ mean,
                                                 const float* __restrict__ Ws,
                                                 const float* __restrict__ Wn,
                                                 const float* __restrict__ bias,
                                                 float* __restrict__ out, int N) {
    __shared__ float sx[32][128];
    __shared__ float sm[32][128];
    int tid = threadIdx.x;
    int r0 = blockIdx.x * 32;

    #pragma unroll
    for (int j = 0; j < 4; ++j) {
        int idx = tid + j * 256;
        int row = idx >> 5;
        int c4 = idx & 31;
        float4 vx = make_float4(0.f, 0.f, 0.f, 0.f);
        float4 vm = make_float4(0.f, 0.f, 0.f, 0.f);
        if (r0 + row < N) {
            vx = ((const float4*)x)[(size_t)(r0 + row) * 32 + c4];
            vm = ((const float4*)mean)[(size_t)(r0 + row) * 32 + c4];
        }
        *(float4*)&sx[row][c4 * 4] = vx;
        *(float4*)&sm[row][c4 * 4] = vm;
    }
    __syncthreads();

    int cg = (tid & 31) * 4;
    int rg = (tid >> 5) * 4;

    float4 bb = *(const float4*)&bias[cg];
    float acc[4][4];
    #pragma unroll
    for (int i = 0; i < 4; ++i) {
        acc[i][0] = bb.x; acc[i][1] = bb.y; acc[i][2] = bb.z; acc[i][3] = bb.w;
    }

    // 4-deep W-row prefetch pipeline
    float4 wsv[4], wnv[4];
    #pragma unroll
    for (int u = 0; u < 4; ++u) {
        wsv[u] = *(const float4*)&Ws[u * 128 + cg];
        wnv[u] = *(const float4*)&Wn[u * 128 + cg];
    }
    for (int k0 = 0; k0 < 128; k0 += 4) {
        float4 nws[4], nwn[4];
        int kp = (k0 + 4 < 128) ? (k0 + 4) : 0;  // wrap: harmless dummy loads on last iter
        #pragma unroll
        for (int u = 0; u < 4; ++u) {
            nws[u] = *(const float4*)&Ws[(kp + u) * 128 + cg];
            nwn[u] = *(const float4*)&Wn[(kp + u) * 128 + cg];
        }
        #pragma unroll
        for (int u = 0; u < 4; ++u) {
            int k = k0 + u;
            #pragma unroll
            for (int i = 0; i < 4; ++i) {
                float a = sx[rg + i][k];
                float m = sm[rg + i][k];
                acc[i][0] = fmaf(a, wsv[u].x, fmaf(m, wnv[u].x, acc[i][0]));
                acc[i][1] = fmaf(a, wsv[u].y, fmaf(m, wnv[u].y, acc[i][1]));
                acc[i][2] = fmaf(a, wsv[u].z, fmaf(m, wnv[u].z, acc[i][2]));
                acc[i][3] = fmaf(a, wsv[u].w, fmaf(m, wnv[u].w, acc[i][3]));
            }
        }
        #pragma unroll
        for (int u = 0; u < 4; ++u) { wsv[u] = nws[u]; wnv[u] = nwn[u]; }
    }

    #pragma unroll
    for (int i = 0; i < 4; ++i) {
        int row = r0 + rg + i;
        if (row < N) {
            float4 o;
            o.x = acc[i][0]; o.y = acc[i][1]; o.z = acc[i][2]; o.w = acc[i][3];
            if (RELU) {
                o.x = fmaxf(o.x, 0.f);
                o.y = fmaxf(o.y, 0.f);
                o.z = fmaxf(o.z, 0.f);
                o.w = fmaxf(o.w, 0.f);
            }
            ((float4*)out)[(size_t)row * 32 + (cg >> 2)] = o;
        }
    }
}

// ---------------- launch ----------------

extern "C" void kernel_launch(void* const* d_in, const int* in_sizes, int n_in,
                              void* d_out, int out_size, void* d_ws, size_t ws_size,
                              hipStream_t stream) {
    const float* feat = (const float*)d_in[0];
    const int* src = (const int*)d_in[1];
    const int* dst = (const int*)d_in[2];
    const float* W1s = (const float*)d_in[3];
    const float* W1n = (const float*)d_in[4];
    const float* b1 = (const float*)d_in[5];
    const float* W2s = (const float*)d_in[6];
    const float* W2n = (const float*)d_in[7];
    const float* b2 = (const float*)d_in[8];
    const float* W3s = (const float*)d_in[9];
    const float* W3n = (const float*)d_in[10];
    const float* b3 = (const float*)d_in[11];
    float* out = (float*)d_out;

    const int N = NN, E = NE;

    char* p = (char*)d_ws;
    auto alloc = [&](size_t bytes) {
        char* q = p;
        p += (bytes + 255) & ~(size_t)255;
        return q;
    };
    int* deg = (int*)alloc((size_t)N * 4);
    int* off = (int*)alloc((size_t)N * 4);
    int* cur = (int*)alloc((size_t)N * 4);
    float* recip = (float*)alloc((size_t)N * 4);
    int* csr = (int*)alloc((size_t)E * 4);
    float* mean = (float*)alloc((size_t)N * F * 4);
    float* h1 = (float*)alloc((size_t)N * F * 4);

    hipMemsetAsync(deg, 0, (size_t)N * 4, stream);
    count_deg<<<(E + 255) / 256, 256, 0, stream>>>(dst, deg, E);
    scan_offsets<<<1, 1024, 0, stream>>>(deg, off, cur, recip, N);
    fill_csr<<<(E + 255) / 256, 256, 0, stream>>>(src, dst, cur, csr, E);

    int aggGrid = (N + 3) / 4;
    int gemmGrid = (N + 31) / 32;

    // layer 1: x = feat -> h1 (relu)
    agg_mean<<<aggGrid, 256, 0, stream>>>(feat, off, deg, recip, csr, mean, N);
    sage_gemm<1><<<gemmGrid, 256, 0, stream>>>(feat, mean, W1s, W1n, b1, h1, N);
    // layer 2: x = h1 -> out (relu)
    agg_mean<<<aggGrid, 256, 0, stream>>>(h1, off, deg, recip, csr, mean, N);
    sage_gemm<1><<<gemmGrid, 256, 0, stream>>>(h1, mean, W2s, W2n, b2, out, N);
    // layer 3: x = out -> out (no relu, in-place safe)
    agg_mean<<<aggGrid, 256, 0, stream>>>(out, off, deg, recip, csr, mean, N);
    sage_gemm<0><<<gemmGrid, 256, 0, stream>>>(out, mean, W3s, W3n, b3, out, N);
}